// Round 3
// baseline (289.548 us; speedup 1.0000x reference)
//
#include <hip/hip_runtime.h>
#include <hip/hip_bf16.h>
#include <math.h>

#define SEQ_LEN 128
#define BATCH   32
#define T       32
#define TT      (T*T)     // 1024
#define TTT     (T*T*T)   // 32768
#define START   30
#define END     31

typedef unsigned long long u64;

// ---- packed (tag, value): one 64-bit word is self-consistent ----
__device__ __forceinline__ u64 pt_pack(int tag, float v) {
    union { float f; unsigned int u; } c; c.f = v;
    return ((u64)(unsigned int)tag << 32) | (u64)c.u;
}
__device__ __forceinline__ float pt_val(u64 w) {
    union { unsigned int u; float f; } c; c.u = (unsigned int)w; return c.f;
}
__device__ __forceinline__ int pt_tag(u64 w) { return (int)(w >> 32); }

__device__ __forceinline__ u64 ald64(const u64* p) {
    return __hip_atomic_load(p, __ATOMIC_RELAXED, __HIP_MEMORY_SCOPE_AGENT);
}
__device__ __forceinline__ void ast64(u64* p, u64 v) {
    __hip_atomic_store(p, v, __ATOMIC_RELAXED, __HIP_MEMORY_SCOPE_AGENT);
}

#define WAITV(n) asm volatile("s_waitcnt vmcnt(" #n ")" ::: "memory")

__device__ __forceinline__ void gload_lds16(const float* g, float* l) {
    __builtin_amdgcn_global_load_lds(
        (const __attribute__((address_space(1))) unsigned int*)(const void*)g,
        (__attribute__((address_space(3))) unsigned int*)(void*)l,
        16, 0, 0);
}

// ---------------------------------------------------------------------------
// Kernel 1: tg_energy gather. ws[0..15] <- per-block partial sums.
// ---------------------------------------------------------------------------
__global__ __launch_bounds__(256) void tg_kernel(const float* __restrict__ scores,
                                                 const int*   __restrict__ target,
                                                 const int*   __restrict__ mask,
                                                 float*       __restrict__ ws) {
    int idx = blockIdx.x * 256 + threadIdx.x;   // idx = s*BATCH + b
    float v = 0.0f;
    if (mask[idx] != 0) {
        v = scores[(size_t)idx * TTT + target[idx]];
    }
    #pragma unroll
    for (int off = 32; off > 0; off >>= 1)
        v += __shfl_down(v, off, 64);
    __shared__ float partial[4];
    int wave = threadIdx.x >> 6;
    int lane = threadIdx.x & 63;
    if (lane == 0) partial[wave] = v;
    __syncthreads();
    if (threadIdx.x == 0)
        ws[blockIdx.x] = partial[0] + partial[1] + partial[2] + partial[3];
}

// ---------------------------------------------------------------------------
// Kernel 2: init tagged partition. buf layout: pt[b][parity][j*32 + i].
// buf1 <- initial partition (tag 1); buf0 <- tag 0 (replay safety).
// ---------------------------------------------------------------------------
__global__ __launch_bounds__(1024) void init_kernel(const float* __restrict__ scores,
                                                    u64* __restrict__ pt64) {
    int b = blockIdx.x, tid = threadIdx.x;
    int x = tid >> 5, y = tid & 31;   // x = i, y = j
    float p1 = scores[(size_t)(0*BATCH + b)*TTT + START*TT + START*T + x];
    float s1 = scores[(size_t)(1*BATCH + b)*TTT + START*TT + x*T + y];
    u64* base = pt64 + (size_t)b * 2 * TT;
    base[TT + y*T + x] = pt_pack(1, p1 + s1);   // buf1[j*32+i]
    base[tid]          = 0ULL;                  // buf0
}

// ---------------------------------------------------------------------------
// Kernel 3: wave-autonomous distributed scan.
// 256 blocks = 32 batches x 8 groups; 384 threads = 4 consumer + 2 streamer
// waves. Consumer wave c owns column j = 4g+c. No barriers in the loop.
// Streamers: depth-4 global_load_lds pipeline, counted vmcnt, LDS flags.
// ---------------------------------------------------------------------------
__global__ __launch_bounds__(384) void scan_wave(const float* __restrict__ scores,
                                                 const int*   __restrict__ maskI,
                                                 u64*         __restrict__ pt64) {
    const int bid  = blockIdx.x;
    const int b    = bid & (BATCH - 1);
    const int g    = bid >> 5;
    const int tid  = threadIdx.x;
    const int w    = tid >> 6;
    const int lane = tid & 63;

    __shared__ float smem[4 * 4096];   // 4 slots x 16KB: [i][c][k]
    __shared__ int   flagLDS[8];       // [streamer(2)][slot(4)]
    __shared__ int   doneLDS[16];      // [consumer(4)][slot(4)]
    __shared__ int   ldsMask[SEQ_LEN];

    if (tid < 8)  flagLDS[tid] = -1;
    if (tid < 16) doneLDS[tid] = -1;
    if (tid < SEQ_LEN) ldsMask[tid] = maskI[tid * BATCH + b];
    __syncthreads();

    u64* ptbase = pt64 + (size_t)b * 2 * TT;
    volatile int* vflag = (volatile int*)flagLDS;
    volatile int* vdone = (volatile int*)doneLDS;

    if (w >= 4) {
        // ------------------------- streamer wave -------------------------
        const int sid = w - 4;
        const float* gbase = scores + (size_t)(sid*16 + (lane >> 5)) * TT
                                    + g*128 + (lane & 31)*4;
        float* lbase = smem + sid*2048;

        auto issue_step = [&](int t) {
            const int slot = t & 3;
            const float* gp = gbase + ((size_t)t * BATCH + b) * TTT;
            float* lp = lbase + slot * 4096;
            #pragma unroll
            for (int ii = 0; ii < 8; ++ii) {
                gload_lds16(gp + (size_t)(2*ii)*TT, lp + ii*256);
            }
        };

        issue_step(2); issue_step(3); issue_step(4); issue_step(5);

        for (int t = 2; t <= 123; ++t) {
            WAITV(24);                         // oldest 8 (step t) retired
            __builtin_amdgcn_sched_barrier(0);
            if (lane == 0) vflag[sid*4 + (t & 3)] = t;
            // backpressure: consumers must have read step t from this slot
            bool ok;
            do {
                int d = vdone[(lane & 3)*4 + (t & 3)];
                ok = (d >= t);
            } while (!__all(ok));
            asm volatile("" ::: "memory");
            issue_step(t + 4);
        }
        WAITV(24); __builtin_amdgcn_sched_barrier(0); if (lane == 0) vflag[sid*4 + (124 & 3)] = 124;
        WAITV(16); __builtin_amdgcn_sched_barrier(0); if (lane == 0) vflag[sid*4 + (125 & 3)] = 125;
        WAITV(8);  __builtin_amdgcn_sched_barrier(0); if (lane == 0) vflag[sid*4 + (126 & 3)] = 126;
        WAITV(0);  __builtin_amdgcn_sched_barrier(0); if (lane == 0) vflag[sid*4 + (127 & 3)] = 127;
    } else {
        // ------------------------- consumer wave -------------------------
        const int c = w;
        const int j = 4*g + c;
        const int h = lane >> 5;
        const int k = lane & 31;

        for (int t = 2; t <= 127; ++t) {
            const int slot = t & 3;
            // wait for score tile (usually already there)
            while (vflag[slot] != t || vflag[4 + slot] != t) {}
            asm volatile("" ::: "memory");

            // precompute m_s and E = exp(s - m_s): OFF the dependency chain
            const float* sl = smem + slot*4096 + c*32 + k;
            float sv[16];
            float mloc = -1e30f;
            #pragma unroll
            for (int m = 0; m < 16; ++m) {
                sv[m] = sl[(h*16 + m) * 128];
                mloc = fmaxf(mloc, sv[m]);
            }
            float ms = fmaxf(mloc, __shfl_xor(mloc, 32, 64));
            float E[16];
            #pragma unroll
            for (int m = 0; m < 16; ++m) E[m] = __expf(sv[m] - ms);
            asm volatile("s_waitcnt lgkmcnt(0)" ::: "memory");
            __builtin_amdgcn_sched_barrier(0);
            if (lane == 0) vdone[c*4 + slot] = t;

            // poll previous partition column j (32 tagged words)
            const u64* pp = ptbase + ((t - 1) & 1)*TT + j*T + k;
            const int tagw = t - 1;
            u64 wv;
            do { wv = ald64(pp); } while (!__all(pt_tag(wv) == tagw));
            float p = pt_val(wv);

            // critical path: mp, w=exp(p-mp), 16 FMA, log, publish
            float mp = p;
            mp = fmaxf(mp, __shfl_xor(mp, 1, 64));
            mp = fmaxf(mp, __shfl_xor(mp, 2, 64));
            mp = fmaxf(mp, __shfl_xor(mp, 4, 64));
            mp = fmaxf(mp, __shfl_xor(mp, 8, 64));
            mp = fmaxf(mp, __shfl_xor(mp, 16, 64));
            float wg = __expf(p - mp);
            float acc = 0.0f;
            #pragma unroll
            for (int m = 0; m < 16; ++m) {
                float wm = __shfl(wg, h*16 + m, 64);
                acc = fmaf(E[m], wm, acc);
            }
            acc += __shfl_xor(acc, 32, 64);

            u64* pn = ptbase + (t & 1)*TT;
            if (ldsMask[t] != 0) {
                float r = ms + mp + __logf(acc);
                if (lane < 32) ast64(pn + k*T + j, pt_pack(t, r));   // [newcol k][row j]
            } else {
                if (lane < 32) ast64(pn + j*T + k, pt_pack(t, p));   // pass-through
            }
        }
    }
}

// ---------------------------------------------------------------------------
// Kernel 4: finalize. out = (z - tg_energy) / BATCH
// ---------------------------------------------------------------------------
__global__ void finalize64(const float* __restrict__ ws, const u64* __restrict__ pt64,
                           float* __restrict__ out) {
    if (threadIdx.x == 0) {
        float tg = 0.f, z = 0.f;
        #pragma unroll
        for (int i = 0; i < 16; ++i) tg += ws[i];
        for (int b = 0; b < BATCH; ++b)
            z += pt_val(pt64[(size_t)(b * 2 + 1) * TT + END * T + END]);
        out[0] = (z - tg) / (float)BATCH;
    }
}

// ---------------------------------------------------------------------------
// Fallback path (small ws): round-1 single-block-per-batch scan.
// ---------------------------------------------------------------------------
__global__ __launch_bounds__(1024) void scan_simple(const float* __restrict__ scores,
                                                    const int*   __restrict__ mask,
                                                    float*       __restrict__ ws) {
    const int b   = blockIdx.x;
    const int tid = threadIdx.x;
    const int j   = tid >> 5;
    __shared__ float pA[TT];
    __shared__ float pB[TT];
    {
        int i  = tid >> 5;
        int jjy = tid & 31;
        float p1 = scores[((size_t)(0*BATCH + b)*T + START)*TT + START*T + i];
        float s1 = scores[((size_t)(1*BATCH + b)*T + START)*TT + i*T + jjy];
        pA[tid] = p1 + s1;
    }
    __syncthreads();
    float* cur = pA;
    float* nxt = pB;
    for (int t = 2; t < SEQ_LEN; ++t) {
        const float* __restrict__ sp = scores + (size_t)(t*BATCH + b)*TTT + tid;
        float buf[T];
        #pragma unroll
        for (int i = 0; i < T; ++i) buf[i] = sp[(size_t)i * TT];
        #pragma unroll
        for (int i = 0; i < T; ++i) buf[i] += cur[i*T + j];
        float m = buf[0];
        #pragma unroll
        for (int i = 1; i < T; ++i) m = fmaxf(m, buf[i]);
        float ssum = 0.0f;
        #pragma unroll
        for (int i = 0; i < T; ++i) ssum += __expf(buf[i] - m);
        float newv = m + __logf(ssum);
        if (mask[t*BATCH + b] == 0) newv = cur[tid];
        nxt[tid] = newv;
        __syncthreads();
        float* tmp = cur; cur = nxt; nxt = tmp;
    }
    if (tid == 0) ws[16 + b] = cur[END*T + END];
}

__global__ void finalize_simple(const float* __restrict__ ws, float* __restrict__ out) {
    if (threadIdx.x == 0) {
        float tg = 0.0f, z = 0.0f;
        #pragma unroll
        for (int i = 0; i < 16; ++i) tg += ws[i];
        #pragma unroll
        for (int i = 0; i < 32; ++i) z += ws[16 + i];
        out[0] = (z - tg) / (float)BATCH;
    }
}

extern "C" void kernel_launch(void* const* d_in, const int* in_sizes, int n_in,
                              void* d_out, int out_size, void* d_ws, size_t ws_size,
                              hipStream_t stream) {
    const float* scores = (const float*)d_in[0];
    const int*   target = (const int*)d_in[1];
    const int*   mask   = (const int*)d_in[2];
    float* out = (float*)d_out;
    float* ws  = (float*)d_ws;
    u64*   pt64 = (u64*)((char*)d_ws + 2048);
    const size_t need = 2048 + (size_t)2 * BATCH * TT * sizeof(u64);

    tg_kernel<<<16, 256, 0, stream>>>(scores, target, mask, ws);
    if (ws_size >= need) {
        init_kernel<<<BATCH, 1024, 0, stream>>>(scores, pt64);
        scan_wave<<<BATCH * 8, 384, 0, stream>>>(scores, mask, pt64);
        finalize64<<<1, 64, 0, stream>>>(ws, pt64, out);
    } else {
        scan_simple<<<BATCH, 1024, 0, stream>>>(scores, mask, ws);
        finalize_simple<<<1, 64, 0, stream>>>(ws, out);
    }
}